// Round 18
// baseline (235.428 us; speedup 1.0000x reference)
//
#include <hip/hip_runtime.h>
#include <hip/hip_fp16.h>
#include <math.h>

#define NN 100000
#define NE 3200000
#define NB 391            // buckets of 256 nodes
#define NBH 256           // histogram partial blocks
#define CH 4096           // edges per partition chunk
#define NPART ((NE + CH - 1) / CH)   // 782

typedef unsigned long long u64;
typedef _Float16 h2 __attribute__((ext_vector_type(2)));

__device__ inline float2 u2f2(unsigned v) {
    __half2 h = *reinterpret_cast<__half2*>(&v);
    return __half22float2(h);
}

#if __has_builtin(__builtin_amdgcn_fdot2)
__device__ inline float dot2acc(unsigned a, unsigned b, float c) {
    union { unsigned u; h2 h; } ca, cb;
    ca.u = a; cb.u = b;
    return __builtin_amdgcn_fdot2(ca.h, cb.h, c, false);   // v_dot2_f32_f16
}
#else
__device__ inline float dot2acc(unsigned a, unsigned b, float c) {
    float2 fa = u2f2(a), fb = u2f2(b);
    return c + fa.x * fb.x + fa.y * fb.y;
}
#endif

// accumulate 8 fp16 (one uint4) into 8 f32
__device__ inline void acc8(float* a, uint4 v) {
    float2 f;
    f = u2f2(v.x); a[0] += f.x; a[1] += f.y;
    f = u2f2(v.y); a[2] += f.x; a[3] += f.y;
    f = u2f2(v.z); a[4] += f.x; a[5] += f.y;
    f = u2f2(v.w); a[6] += f.x; a[7] += f.y;
}

// ---------------- bucket histogram: per-block partials, no global pre-zero ----------------
__global__ __launch_bounds__(256) void bhist_kernel(const int* __restrict__ dst,
                                                    int* __restrict__ part, int e) {
    __shared__ int h[NB];
    int tid = threadIdx.x;
    for (int i = tid; i < NB; i += 256) h[i] = 0;
    __syncthreads();
    for (int i = blockIdx.x * 256 + tid; i < e; i += NBH * 256)
        atomicAdd(&h[dst[i] >> 8], 1);
    __syncthreads();
    for (int i = tid; i < NB; i += 256)
        part[blockIdx.x * NB + i] = h[i];     // overwrite: deterministic, no memset
}

// ---------------- column-sum partials + exclusive scan ----------------
__global__ __launch_bounds__(512) void bscan_kernel(const int* __restrict__ part,
                                                    int* __restrict__ bhist,
                                                    int* __restrict__ boffs,
                                                    int* __restrict__ cursor) {
    __shared__ int s[512];
    int tid = threadIdx.x;
    int v = 0;
    if (tid < NB) {
#pragma unroll 8
        for (int b = 0; b < NBH; ++b) v += part[b * NB + tid];
        bhist[tid] = v;
    }
    s[tid] = (tid < NB) ? v : 0;
    __syncthreads();
    for (int off = 1; off < 512; off <<= 1) {
        int t = (tid >= off) ? s[tid - off] : 0;
        __syncthreads();
        s[tid] += t;
        __syncthreads();
    }
    if (tid < NB) {
        int ex = s[tid] - v;
        boffs[tid] = ex;
        cursor[tid] = ex;
    }
}

// ---------------- partition: lean 5-phase counting-sort, 512 threads ----------------
__global__ __launch_bounds__(512) void partition_kernel(
        const int* __restrict__ src, const int* __restrict__ dst,
        int* __restrict__ cursor, int* __restrict__ adj, int e) {
    __shared__ int scnt[NB];
    __shared__ int sbase[NB];
    __shared__ int lexcl[NB];
    __shared__ int cur[NB];
    __shared__ int s[512];
    __shared__ int sdata[CH];

    int tid = threadIdx.x;
    int chunk0 = blockIdx.x * CH;

    for (int i = tid; i < NB; i += 512) scnt[i] = 0;
    __syncthreads();

#pragma unroll
    for (int k = 0; k < CH / 512; ++k) {
        int i = chunk0 + k * 512 + tid;
        if (i < e) atomicAdd(&scnt[dst[i] >> 8], 1);
    }
    __syncthreads();

    for (int b = tid; b < NB; b += 512)
        if (scnt[b]) sbase[b] = atomicAdd(&cursor[b], scnt[b]);

    s[tid] = (tid < NB) ? scnt[tid] : 0;
    __syncthreads();
    for (int off = 1; off < 512; off <<= 1) {
        int t = (tid >= off) ? s[tid - off] : 0;
        __syncthreads();
        s[tid] += t;
        __syncthreads();
    }
    if (tid < NB) {
        int ex = s[tid] - scnt[tid];
        lexcl[tid] = ex;
        cur[tid] = ex;
    }
    __syncthreads();

#pragma unroll
    for (int k = 0; k < CH / 512; ++k) {
        int i = chunk0 + k * 512 + tid;
        if (i < e) {
            int sv = src[i], d = dst[i];
            int b = d >> 8;
            int p = atomicAdd(&cur[b], 1);
            sdata[p] = (sv << 8) | (d & 255);
        }
    }
    __syncthreads();

    for (int b = tid; b < NB; b += 512) {
        int cb = scnt[b];
        if (cb) {
            int base = sbase[b];
            int start = lexcl[b];
            for (int k2 = 0; k2 < cb; ++k2)
                adj[base + k2] = sdata[start + k2];
        }
    }
}

// ---------------- per-bucket node-sort -> adj2 + rowptr + dinv (512 threads) ----------------
__global__ __launch_bounds__(512) void csr_kernel(
        const int* __restrict__ bhist, const int* __restrict__ boffs,
        const int* __restrict__ adj, int* __restrict__ adj2,
        int* __restrict__ rowptr, float* __restrict__ dinv, int n) {
    __shared__ int cnt[256];
    __shared__ int s[256];
    __shared__ int cur[256];
    int tid = threadIdx.x;
    int b = blockIdx.x;
    if (tid < 256) cnt[tid] = 0;
    __syncthreads();
    int ebeg = boffs[b], ecnt = bhist[b];
    for (int j = tid; j < ecnt; j += 512)
        atomicAdd(&cnt[adj[ebeg + j] & 255], 1);
    __syncthreads();
    int v = 0;
    if (tid < 256) { v = cnt[tid]; s[tid] = v; }
    __syncthreads();
    for (int off = 1; off < 256; off <<= 1) {
        int t = 0;
        if (tid < 256 && tid >= off) t = s[tid - off];
        __syncthreads();
        if (tid < 256) s[tid] += t;
        __syncthreads();
    }
    if (tid < 256) {
        int excl = s[tid] - v;
        cur[tid] = excl;
        int node = b * 256 + tid;
        if (node < n) {
            rowptr[node] = ebeg + excl;
            dinv[node] = rsqrtf((float)v + 1.0f);
        }
        if (node == n) rowptr[n] = ebeg + excl;   // sentinel == e
    }
    __syncthreads();
    for (int j = tid; j < ecnt; j += 512) {
        int w = adj[ebeg + j];
        int p = atomicAdd(&cur[w & 255], 1);
        adj2[ebeg + p] = w >> 8;
    }
}

// ---------------- layer 1 GEMM: split fp16 tables g1a (cols 0-15), g1b (cols 16-31) ----------------
__global__ __launch_bounds__(256) void gemm1_kernel(
        const float* __restrict__ x, const float* __restrict__ W1,
        const float* __restrict__ dinv, __half* __restrict__ g1a,
        __half* __restrict__ g1b, int n) {
    __shared__ float sW[64 * 32];     // sW[k*32+c] = W1[c*64+k]
    __shared__ float sX[32 * 65];     // padded stride 65
    int tid = threadIdx.x;
    for (int idx = tid; idx < 2048; idx += 256) {
        int k = idx >> 5, c = idx & 31;
        sW[idx] = W1[c * 64 + k];
    }
    int row0 = blockIdx.x * 32;
    for (int idx = tid; idx < 512; idx += 256) {   // 512 float4 = 32 rows x 16
        int r = idx >> 4, q = idx & 15;
        int grow = row0 + r;
        float4 v = (grow < n) ? ((const float4*)x)[(size_t)grow * 16 + q]
                              : make_float4(0.f, 0.f, 0.f, 0.f);
        float* dp = &sX[r * 65 + q * 4];
        dp[0] = v.x; dp[1] = v.y; dp[2] = v.z; dp[3] = v.w;
    }
    __syncthreads();
    int r = tid >> 3, cg = tid & 7;
    const float4* sW4 = (const float4*)sW;
    float4 acc = make_float4(0.f, 0.f, 0.f, 0.f);
#pragma unroll
    for (int k = 0; k < 64; ++k) {
        float xk = sX[r * 65 + k];
        float4 w = sW4[k * 8 + cg];
        acc.x += xk * w.x; acc.y += xk * w.y; acc.z += xk * w.z; acc.w += xk * w.w;
    }
    int grow = row0 + r;
    if (grow < n) {
        float di = dinv[grow];
        __half2 h0 = __float22half2_rn(make_float2(acc.x * di, acc.y * di));
        __half2 h1 = __float22half2_rn(make_float2(acc.z * di, acc.w * di));
        uint2 packed;
        packed.x = *(unsigned*)&h0;
        packed.y = *(unsigned*)&h1;
        if (cg < 4) ((uint2*)g1a)[(size_t)grow * 4 + cg] = packed;
        else        ((uint2*)g1b)[(size_t)grow * 4 + (cg - 4)] = packed;
    }
}

// ---------------- layer 1 aggregation: 4 threads/node (2 col-halves x 2 neighbor-slices),
//                  uint4 gathers: 2 L2 requests/edge/pass (was 8) ----------------
__global__ __launch_bounds__(256) void agg1_kernel(
        const int* __restrict__ rowptr, const int* __restrict__ adj2,
        const float* __restrict__ dinv, const __half* __restrict__ gh,
        const float* __restrict__ b1, float* __restrict__ agg1, int n, int pass) {
    int t = blockIdx.x * blockDim.x + threadIdx.x;
    int node = t >> 2;
    if (node >= n) return;
    int sub = t & 3;
    int slice = sub >> 1, ch = sub & 1;
    const uint4* G = (const uint4*)gh;         // row i = G[i*2 + ch]
    float acc[8] = {0.f, 0.f, 0.f, 0.f, 0.f, 0.f, 0.f, 0.f};
    if (slice == 0)                             // self-loop once
        acc8(acc, G[(size_t)node * 2 + ch]);
    int beg = rowptr[node], end = rowptr[node + 1];
    int deg = end - beg;
    int half0 = (deg + 1) >> 1;
    int j    = beg + slice * half0;
    int jend = slice ? end : beg + half0;
    for (; j + 7 < jend; j += 8) {
        int s0 = adj2[j],     s1 = adj2[j + 1], s2 = adj2[j + 2], s3 = adj2[j + 3];
        int s4 = adj2[j + 4], s5 = adj2[j + 5], s6 = adj2[j + 6], s7 = adj2[j + 7];
        uint4 v0 = G[(size_t)s0 * 2 + ch];
        uint4 v1 = G[(size_t)s1 * 2 + ch];
        uint4 v2 = G[(size_t)s2 * 2 + ch];
        uint4 v3 = G[(size_t)s3 * 2 + ch];
        uint4 v4 = G[(size_t)s4 * 2 + ch];
        uint4 v5 = G[(size_t)s5 * 2 + ch];
        uint4 v6 = G[(size_t)s6 * 2 + ch];
        uint4 v7 = G[(size_t)s7 * 2 + ch];
        acc8(acc, v0); acc8(acc, v1); acc8(acc, v2); acc8(acc, v3);
        acc8(acc, v4); acc8(acc, v5); acc8(acc, v6); acc8(acc, v7);
    }
    for (; j + 3 < jend; j += 4) {
        int s0 = adj2[j], s1 = adj2[j + 1], s2 = adj2[j + 2], s3 = adj2[j + 3];
        uint4 v0 = G[(size_t)s0 * 2 + ch];
        uint4 v1 = G[(size_t)s1 * 2 + ch];
        uint4 v2 = G[(size_t)s2 * 2 + ch];
        uint4 v3 = G[(size_t)s3 * 2 + ch];
        acc8(acc, v0); acc8(acc, v1); acc8(acc, v2); acc8(acc, v3);
    }
    for (; j < jend; ++j)
        acc8(acc, G[(size_t)adj2[j] * 2 + ch]);
    // combine the two neighbor slices (lanes differ in bit 1)
#pragma unroll
    for (int k = 0; k < 8; ++k)
        acc[k] += __shfl_xor(acc[k], 2, 64);
    if (slice == 0) {
        float di = dinv[node];
        float4 bb0 = ((const float4*)b1)[pass * 4 + ch * 2];
        float4 bb1 = ((const float4*)b1)[pass * 4 + ch * 2 + 1];
        float4 o0 = make_float4(bb0.x + di * acc[0], bb0.y + di * acc[1],
                                bb0.z + di * acc[2], bb0.w + di * acc[3]);
        float4 o1 = make_float4(bb1.x + di * acc[4], bb1.y + di * acc[5],
                                bb1.z + di * acc[6], bb1.w + di * acc[7]);
        ((float4*)agg1)[(size_t)node * 8 + pass * 4 + ch * 2]     = o0;
        ((float4*)agg1)[(size_t)node * 8 + pass * 4 + ch * 2 + 1] = o1;
    }
}

// ---------------- layer 2 GEMM: 64-row tile, float4 W reads ----------------
__global__ __launch_bounds__(256) void gemm2_kernel(
        const float* __restrict__ agg1, const float* __restrict__ W2,
        const float* __restrict__ dinv, __half* __restrict__ g2h, int n) {
    __shared__ float sW[32 * 16];     // sW[k*16+c] = W2[c*32+k]
    __shared__ float sH[64 * 33];     // padded
    int tid = threadIdx.x;
    for (int idx = tid; idx < 512; idx += 256) {
        int k = idx >> 4, c = idx & 15;
        sW[idx] = W2[c * 32 + k];
    }
    int row0 = blockIdx.x * 64;
    for (int idx = tid; idx < 512; idx += 256) {   // 512 float4 = 64 rows x 8
        int r = idx >> 3, q = idx & 7;
        int grow = row0 + r;
        float4 v = (grow < n) ? ((const float4*)agg1)[(size_t)grow * 8 + q]
                              : make_float4(0.f, 0.f, 0.f, 0.f);
        float* dp = &sH[r * 33 + q * 4];
        dp[0] = fmaxf(v.x, 0.f); dp[1] = fmaxf(v.y, 0.f);
        dp[2] = fmaxf(v.z, 0.f); dp[3] = fmaxf(v.w, 0.f);
    }
    __syncthreads();
    int r = tid >> 2, cg = tid & 3;
    const float4* sW4 = (const float4*)sW;
    float4 acc = make_float4(0.f, 0.f, 0.f, 0.f);
#pragma unroll
    for (int k = 0; k < 32; ++k) {
        float hk = sH[r * 33 + k];
        float4 w = sW4[k * 4 + cg];
        acc.x += hk * w.x; acc.y += hk * w.y; acc.z += hk * w.z; acc.w += hk * w.w;
    }
    int grow = row0 + r;
    if (grow < n) {
        float di = dinv[grow];
        __half2 h0 = __float22half2_rn(make_float2(acc.x * di, acc.y * di));
        __half2 h1 = __float22half2_rn(make_float2(acc.z * di, acc.w * di));
        uint2 packed;
        packed.x = *(unsigned*)&h0;
        packed.y = *(unsigned*)&h1;
        ((uint2*)g2h)[(size_t)grow * 4 + cg] = packed;
    }
}

// ---------------- layer 2 aggregation: 4 threads/node, uint4 gathers ----------------
__global__ __launch_bounds__(256) void agg2_kernel(
        const int* __restrict__ rowptr, const int* __restrict__ adj2,
        const float* __restrict__ dinv, const __half* __restrict__ g2h,
        const float* __restrict__ b2, __half* __restrict__ zh, int n) {
    int t = blockIdx.x * blockDim.x + threadIdx.x;
    int node = t >> 2;
    if (node >= n) return;
    int sub = t & 3;
    int slice = sub >> 1, ch = sub & 1;
    const uint4* G = (const uint4*)g2h;        // row i = G[i*2 + ch]
    float acc[8] = {0.f, 0.f, 0.f, 0.f, 0.f, 0.f, 0.f, 0.f};
    if (slice == 0)
        acc8(acc, G[(size_t)node * 2 + ch]);
    int beg = rowptr[node], end = rowptr[node + 1];
    int deg = end - beg;
    int half0 = (deg + 1) >> 1;
    int j    = beg + slice * half0;
    int jend = slice ? end : beg + half0;
    for (; j + 7 < jend; j += 8) {
        int s0 = adj2[j],     s1 = adj2[j + 1], s2 = adj2[j + 2], s3 = adj2[j + 3];
        int s4 = adj2[j + 4], s5 = adj2[j + 5], s6 = adj2[j + 6], s7 = adj2[j + 7];
        uint4 v0 = G[(size_t)s0 * 2 + ch];
        uint4 v1 = G[(size_t)s1 * 2 + ch];
        uint4 v2 = G[(size_t)s2 * 2 + ch];
        uint4 v3 = G[(size_t)s3 * 2 + ch];
        uint4 v4 = G[(size_t)s4 * 2 + ch];
        uint4 v5 = G[(size_t)s5 * 2 + ch];
        uint4 v6 = G[(size_t)s6 * 2 + ch];
        uint4 v7 = G[(size_t)s7 * 2 + ch];
        acc8(acc, v0); acc8(acc, v1); acc8(acc, v2); acc8(acc, v3);
        acc8(acc, v4); acc8(acc, v5); acc8(acc, v6); acc8(acc, v7);
    }
    for (; j + 3 < jend; j += 4) {
        int s0 = adj2[j], s1 = adj2[j + 1], s2 = adj2[j + 2], s3 = adj2[j + 3];
        uint4 v0 = G[(size_t)s0 * 2 + ch];
        uint4 v1 = G[(size_t)s1 * 2 + ch];
        uint4 v2 = G[(size_t)s2 * 2 + ch];
        uint4 v3 = G[(size_t)s3 * 2 + ch];
        acc8(acc, v0); acc8(acc, v1); acc8(acc, v2); acc8(acc, v3);
    }
    for (; j < jend; ++j)
        acc8(acc, G[(size_t)adj2[j] * 2 + ch]);
#pragma unroll
    for (int k = 0; k < 8; ++k)
        acc[k] += __shfl_xor(acc[k], 2, 64);
    if (slice == 0) {
        float di = dinv[node];
        float4 bb0 = ((const float4*)b2)[ch * 2];
        float4 bb1 = ((const float4*)b2)[ch * 2 + 1];
        __half2 p0 = __float22half2_rn(make_float2(bb0.x + di * acc[0], bb0.y + di * acc[1]));
        __half2 p1 = __float22half2_rn(make_float2(bb0.z + di * acc[2], bb0.w + di * acc[3]));
        __half2 p2 = __float22half2_rn(make_float2(bb1.x + di * acc[4], bb1.y + di * acc[5]));
        __half2 p3 = __float22half2_rn(make_float2(bb1.z + di * acc[6], bb1.w + di * acc[7]));
        uint4 packed;
        packed.x = *(unsigned*)&p0; packed.y = *(unsigned*)&p1;
        packed.z = *(unsigned*)&p2; packed.w = *(unsigned*)&p3;
        ((uint4*)zh)[(size_t)node * 2 + ch] = packed;
    }
}

// ---------------- decode: pair-lane, 2 edges per lane-pair ----------------
__global__ __launch_bounds__(256) void decode_kernel(
        const int* __restrict__ src, const int* __restrict__ dst,
        const __half* __restrict__ zh, float* __restrict__ out, int e) {
    int t = blockIdx.x * blockDim.x + threadIdx.x;
    int pair = t >> 1;                 // pair of consecutive edges
    int e0 = pair * 2;
    if (e0 >= e) return;
    int half = t & 1;
    u64 sv = *(const u64*)(src + e0);
    u64 dv = *(const u64*)(dst + e0);
    int s0 = (int)(unsigned)sv, s1 = (int)(sv >> 32);
    int d0 = (int)(unsigned)dv, d1 = (int)(dv >> 32);
    uint4 a0 = *((const uint4*)(zh + (size_t)s0 * 16) + half);
    uint4 b0 = *((const uint4*)(zh + (size_t)d0 * 16) + half);
    uint4 a1 = *((const uint4*)(zh + (size_t)s1 * 16) + half);
    uint4 b1 = *((const uint4*)(zh + (size_t)d1 * 16) + half);
    float p0 = 0.f, p1 = 0.f;
    p0 = dot2acc(a0.x, b0.x, p0); p0 = dot2acc(a0.y, b0.y, p0);
    p0 = dot2acc(a0.z, b0.z, p0); p0 = dot2acc(a0.w, b0.w, p0);
    p1 = dot2acc(a1.x, b1.x, p1); p1 = dot2acc(a1.y, b1.y, p1);
    p1 = dot2acc(a1.z, b1.z, p1); p1 = dot2acc(a1.w, b1.w, p1);
    float t0 = p0 + __shfl_xor(p0, 1, 64);
    float t1 = p1 + __shfl_xor(p1, 1, 64);
    if (half == 0) {
        float2 o;
        o.x = 1.0f / (1.0f + expf(-t0));
        o.y = 1.0f / (1.0f + expf(-t1));
        ((float2*)out)[pair] = o;
    }
}

extern "C" void kernel_launch(void* const* d_in, const int* in_sizes, int n_in,
                              void* d_out, int out_size, void* d_ws, size_t ws_size,
                              hipStream_t stream) {
    const float* x   = (const float*)d_in[0];
    const int* eidx  = (const int*)d_in[1];
    const float* W1  = (const float*)d_in[2];
    const float* b1  = (const float*)d_in[3];
    const float* W2  = (const float*)d_in[4];
    const float* b2  = (const float*)d_in[5];
    float* out = (float*)d_out;

    const int n = NN;
    const int e = NE;
    const int* src = eidx;
    const int* dst = eidx + e;

    // workspace layout (all segments 16B-aligned)
    int* bhist   = (int*)d_ws;                 // 512
    int* boffs   = bhist + 512;                // 512
    int* cursor  = boffs + 512;                // 512
    int* rowptr  = cursor + 512;               // NN+1 (pad 100004)
    int* adj     = rowptr + 100004;            // NE packed (dead after csr)
    int* adj2    = adj + e;                    // NE node-sorted srcs
    float* dinv  = (float*)(adj2 + e);         // NN
    __half* g1a  = (__half*)adj;               // alias: NN*16 halves (3.2MB) - cols 0..15
    __half* g1b  = g1a + (size_t)n * 16;       // NN*16 halves (3.2MB) - cols 16..31
    float* agg1  = dinv + n;                   // NN*32 f32
    __half* g2h  = (__half*)(agg1 + (size_t)n * 32);   // NN*16 halves
    __half* zh   = g2h + (size_t)n * 16;               // NN*16 halves
    int* part    = (int*)(zh + (size_t)n * 16);        // NBH*NB partial histograms

    dim3 blk(256);

    // CSR build
    bhist_kernel<<<NBH, blk, 0, stream>>>(dst, part, e);
    bscan_kernel<<<1, 512, 0, stream>>>(part, bhist, boffs, cursor);
    partition_kernel<<<NPART, 512, 0, stream>>>(src, dst, cursor, adj, e);
    csr_kernel<<<NB, 512, 0, stream>>>(bhist, boffs, adj, adj2, rowptr, dinv, n);

    // layer 1
    gemm1_kernel<<<(n + 31) / 32, blk, 0, stream>>>(x, W1, dinv, g1a, g1b, n);
    agg1_kernel<<<(n * 4 + 255) / 256, blk, 0, stream>>>(rowptr, adj2, dinv, g1a, b1, agg1, n, 0);
    agg1_kernel<<<(n * 4 + 255) / 256, blk, 0, stream>>>(rowptr, adj2, dinv, g1b, b1, agg1, n, 1);

    // layer 2
    gemm2_kernel<<<(n + 63) / 64, blk, 0, stream>>>(agg1, W2, dinv, g2h, n);
    agg2_kernel<<<(n * 4 + 255) / 256, blk, 0, stream>>>(rowptr, adj2, dinv, g2h, b2, zh, n);

    // decode: lane-pair handles 2 edges -> e threads total
    decode_kernel<<<(e + 255) / 256, blk, 0, stream>>>(src, dst, zh, out, e);
}

// Round 19
// 230.130 us; speedup vs baseline: 1.0230x; 1.0230x over previous
//
#include <hip/hip_runtime.h>
#include <hip/hip_fp16.h>
#include <math.h>

#define NN 100000
#define NE 3200000
#define NB 391            // buckets of 256 nodes
#define NBH 256           // histogram partial blocks
#define CH 4096           // edges per partition chunk
#define NPART ((NE + CH - 1) / CH)   // 782

typedef unsigned long long u64;
typedef _Float16 h2 __attribute__((ext_vector_type(2)));

__device__ inline float2 u2f2(unsigned v) {
    __half2 h = *reinterpret_cast<__half2*>(&v);
    return __half22float2(h);
}

#if __has_builtin(__builtin_amdgcn_fdot2)
__device__ inline float dot2acc(unsigned a, unsigned b, float c) {
    union { unsigned u; h2 h; } ca, cb;
    ca.u = a; cb.u = b;
    return __builtin_amdgcn_fdot2(ca.h, cb.h, c, false);   // v_dot2_f32_f16
}
#else
__device__ inline float dot2acc(unsigned a, unsigned b, float c) {
    float2 fa = u2f2(a), fb = u2f2(b);
    return c + fa.x * fb.x + fa.y * fb.y;
}
#endif

// accumulate 8 fp16 (one uint4) into 8 f32
__device__ inline void acc8(float* a, uint4 v) {
    float2 f;
    f = u2f2(v.x); a[0] += f.x; a[1] += f.y;
    f = u2f2(v.y); a[2] += f.x; a[3] += f.y;
    f = u2f2(v.z); a[4] += f.x; a[5] += f.y;
    f = u2f2(v.w); a[6] += f.x; a[7] += f.y;
}

// ---------------- bucket histogram: per-block partials, no global pre-zero ----------------
__global__ __launch_bounds__(256) void bhist_kernel(const int* __restrict__ dst,
                                                    int* __restrict__ part, int e) {
    __shared__ int h[NB];
    int tid = threadIdx.x;
    for (int i = tid; i < NB; i += 256) h[i] = 0;
    __syncthreads();
    for (int i = blockIdx.x * 256 + tid; i < e; i += NBH * 256)
        atomicAdd(&h[dst[i] >> 8], 1);
    __syncthreads();
    for (int i = tid; i < NB; i += 256)
        part[blockIdx.x * NB + i] = h[i];     // overwrite: deterministic, no memset
}

// ---------------- column-sum partials + exclusive scan ----------------
__global__ __launch_bounds__(512) void bscan_kernel(const int* __restrict__ part,
                                                    int* __restrict__ bhist,
                                                    int* __restrict__ boffs,
                                                    int* __restrict__ cursor) {
    __shared__ int s[512];
    int tid = threadIdx.x;
    int v = 0;
    if (tid < NB) {
#pragma unroll 8
        for (int b = 0; b < NBH; ++b) v += part[b * NB + tid];
        bhist[tid] = v;
    }
    s[tid] = (tid < NB) ? v : 0;
    __syncthreads();
    for (int off = 1; off < 512; off <<= 1) {
        int t = (tid >= off) ? s[tid - off] : 0;
        __syncthreads();
        s[tid] += t;
        __syncthreads();
    }
    if (tid < NB) {
        int ex = s[tid] - v;
        boffs[tid] = ex;
        cursor[tid] = ex;
    }
}

// ---------------- partition: lean counting-sort, 512 threads, register-cached edges ----------------
// Phase 1 loads src+dst ONCE and keeps (packed, bucket) in registers; phase 4 uses
// registers (no 25.6MB re-read of the edge streams).
__global__ __launch_bounds__(512) void partition_kernel(
        const int* __restrict__ src, const int* __restrict__ dst,
        int* __restrict__ cursor, int* __restrict__ adj, int e) {
    __shared__ int scnt[NB];
    __shared__ int sbase[NB];
    __shared__ int lexcl[NB];
    __shared__ int cur[NB];
    __shared__ int s[512];
    __shared__ int sdata[CH];

    int tid = threadIdx.x;
    int chunk0 = blockIdx.x * CH;

    for (int i = tid; i < NB; i += 512) scnt[i] = 0;
    __syncthreads();

    // phase 1: load + count, cache in registers (CH/512 = 8 edges/thread)
    unsigned pk[8];
    int bk[8];
#pragma unroll
    for (int k = 0; k < 8; ++k) {
        int i = chunk0 + k * 512 + tid;
        bk[k] = -1;
        pk[k] = 0;
        if (i < e) {
            int sv = src[i], d = dst[i];
            int b = d >> 8;
            bk[k] = b;
            pk[k] = (unsigned)((sv << 8) | (d & 255));
            atomicAdd(&scnt[b], 1);
        }
    }
    __syncthreads();

    // phase 2: reserve global windows
    for (int b = tid; b < NB; b += 512)
        if (scnt[b]) sbase[b] = atomicAdd(&cursor[b], scnt[b]);

    // phase 3: exclusive scan of scnt
    s[tid] = (tid < NB) ? scnt[tid] : 0;
    __syncthreads();
    for (int off = 1; off < 512; off <<= 1) {
        int t = (tid >= off) ? s[tid - off] : 0;
        __syncthreads();
        s[tid] += t;
        __syncthreads();
    }
    if (tid < NB) {
        int ex = s[tid] - scnt[tid];
        lexcl[tid] = ex;
        cur[tid] = ex;
    }
    __syncthreads();

    // phase 4: permute registers into LDS, bucket-grouped (no global loads)
#pragma unroll
    for (int k = 0; k < 8; ++k) {
        if (bk[k] >= 0) {
            int p = atomicAdd(&cur[bk[k]], 1);
            sdata[p] = (int)pk[k];
        }
    }
    __syncthreads();

    // phase 5: per-bucket contiguous emission
    for (int b = tid; b < NB; b += 512) {
        int cb = scnt[b];
        if (cb) {
            int base = sbase[b];
            int start = lexcl[b];
            for (int k2 = 0; k2 < cb; ++k2)
                adj[base + k2] = sdata[start + k2];
        }
    }
}

// ---------------- per-bucket node-sort -> adj2 + rowptr + dinv (512 threads) ----------------
__global__ __launch_bounds__(512) void csr_kernel(
        const int* __restrict__ bhist, const int* __restrict__ boffs,
        const int* __restrict__ adj, int* __restrict__ adj2,
        int* __restrict__ rowptr, float* __restrict__ dinv, int n) {
    __shared__ int cnt[256];
    __shared__ int s[256];
    __shared__ int cur[256];
    int tid = threadIdx.x;
    int b = blockIdx.x;
    if (tid < 256) cnt[tid] = 0;
    __syncthreads();
    int ebeg = boffs[b], ecnt = bhist[b];
    for (int j = tid; j < ecnt; j += 512)
        atomicAdd(&cnt[adj[ebeg + j] & 255], 1);
    __syncthreads();
    int v = 0;
    if (tid < 256) { v = cnt[tid]; s[tid] = v; }
    __syncthreads();
    for (int off = 1; off < 256; off <<= 1) {
        int t = 0;
        if (tid < 256 && tid >= off) t = s[tid - off];
        __syncthreads();
        if (tid < 256) s[tid] += t;
        __syncthreads();
    }
    if (tid < 256) {
        int excl = s[tid] - v;
        cur[tid] = excl;
        int node = b * 256 + tid;
        if (node < n) {
            rowptr[node] = ebeg + excl;
            dinv[node] = rsqrtf((float)v + 1.0f);
        }
        if (node == n) rowptr[n] = ebeg + excl;   // sentinel == e
    }
    __syncthreads();
    for (int j = tid; j < ecnt; j += 512) {
        int w = adj[ebeg + j];
        int p = atomicAdd(&cur[w & 255], 1);
        adj2[ebeg + p] = w >> 8;
    }
}

// ---------------- layer 1 GEMM: split fp16 tables g1a (cols 0-15), g1b (cols 16-31) ----------------
__global__ __launch_bounds__(256) void gemm1_kernel(
        const float* __restrict__ x, const float* __restrict__ W1,
        const float* __restrict__ dinv, __half* __restrict__ g1a,
        __half* __restrict__ g1b, int n) {
    __shared__ float sW[64 * 32];     // sW[k*32+c] = W1[c*64+k]
    __shared__ float sX[32 * 65];     // padded stride 65
    int tid = threadIdx.x;
    for (int idx = tid; idx < 2048; idx += 256) {
        int k = idx >> 5, c = idx & 31;
        sW[idx] = W1[c * 64 + k];
    }
    int row0 = blockIdx.x * 32;
    for (int idx = tid; idx < 512; idx += 256) {   // 512 float4 = 32 rows x 16
        int r = idx >> 4, q = idx & 15;
        int grow = row0 + r;
        float4 v = (grow < n) ? ((const float4*)x)[(size_t)grow * 16 + q]
                              : make_float4(0.f, 0.f, 0.f, 0.f);
        float* dp = &sX[r * 65 + q * 4];
        dp[0] = v.x; dp[1] = v.y; dp[2] = v.z; dp[3] = v.w;
    }
    __syncthreads();
    int r = tid >> 3, cg = tid & 7;
    const float4* sW4 = (const float4*)sW;
    float4 acc = make_float4(0.f, 0.f, 0.f, 0.f);
#pragma unroll
    for (int k = 0; k < 64; ++k) {
        float xk = sX[r * 65 + k];
        float4 w = sW4[k * 8 + cg];
        acc.x += xk * w.x; acc.y += xk * w.y; acc.z += xk * w.z; acc.w += xk * w.w;
    }
    int grow = row0 + r;
    if (grow < n) {
        float di = dinv[grow];
        __half2 h0 = __float22half2_rn(make_float2(acc.x * di, acc.y * di));
        __half2 h1 = __float22half2_rn(make_float2(acc.z * di, acc.w * di));
        uint2 packed;
        packed.x = *(unsigned*)&h0;
        packed.y = *(unsigned*)&h1;
        if (cg < 4) ((uint2*)g1a)[(size_t)grow * 4 + cg] = packed;
        else        ((uint2*)g1b)[(size_t)grow * 4 + (cg - 4)] = packed;
    }
}

// ---------------- layer 1 aggregation: 4 threads/node, uint4 gathers;
//                  output = fp16 relu(b1 + dinv*acc)  (feeds gemm2 directly) ----------------
__global__ __launch_bounds__(256) void agg1_kernel(
        const int* __restrict__ rowptr, const int* __restrict__ adj2,
        const float* __restrict__ dinv, const __half* __restrict__ gh,
        const float* __restrict__ b1, __half* __restrict__ agg1h, int n, int pass) {
    int t = blockIdx.x * blockDim.x + threadIdx.x;
    int node = t >> 2;
    if (node >= n) return;
    int sub = t & 3;
    int slice = sub >> 1, ch = sub & 1;
    const uint4* G = (const uint4*)gh;         // row i = G[i*2 + ch]
    float acc[8] = {0.f, 0.f, 0.f, 0.f, 0.f, 0.f, 0.f, 0.f};
    if (slice == 0)                             // self-loop once
        acc8(acc, G[(size_t)node * 2 + ch]);
    int beg = rowptr[node], end = rowptr[node + 1];
    int deg = end - beg;
    int half0 = (deg + 1) >> 1;
    int j    = beg + slice * half0;
    int jend = slice ? end : beg + half0;
    for (; j + 7 < jend; j += 8) {
        int s0 = adj2[j],     s1 = adj2[j + 1], s2 = adj2[j + 2], s3 = adj2[j + 3];
        int s4 = adj2[j + 4], s5 = adj2[j + 5], s6 = adj2[j + 6], s7 = adj2[j + 7];
        uint4 v0 = G[(size_t)s0 * 2 + ch];
        uint4 v1 = G[(size_t)s1 * 2 + ch];
        uint4 v2 = G[(size_t)s2 * 2 + ch];
        uint4 v3 = G[(size_t)s3 * 2 + ch];
        uint4 v4 = G[(size_t)s4 * 2 + ch];
        uint4 v5 = G[(size_t)s5 * 2 + ch];
        uint4 v6 = G[(size_t)s6 * 2 + ch];
        uint4 v7 = G[(size_t)s7 * 2 + ch];
        acc8(acc, v0); acc8(acc, v1); acc8(acc, v2); acc8(acc, v3);
        acc8(acc, v4); acc8(acc, v5); acc8(acc, v6); acc8(acc, v7);
    }
    for (; j + 3 < jend; j += 4) {
        int s0 = adj2[j], s1 = adj2[j + 1], s2 = adj2[j + 2], s3 = adj2[j + 3];
        uint4 v0 = G[(size_t)s0 * 2 + ch];
        uint4 v1 = G[(size_t)s1 * 2 + ch];
        uint4 v2 = G[(size_t)s2 * 2 + ch];
        uint4 v3 = G[(size_t)s3 * 2 + ch];
        acc8(acc, v0); acc8(acc, v1); acc8(acc, v2); acc8(acc, v3);
    }
    for (; j < jend; ++j)
        acc8(acc, G[(size_t)adj2[j] * 2 + ch]);
#pragma unroll
    for (int k = 0; k < 8; ++k)
        acc[k] += __shfl_xor(acc[k], 2, 64);
    if (slice == 0) {
        float di = dinv[node];
        float4 bb0 = ((const float4*)b1)[pass * 4 + ch * 2];
        float4 bb1 = ((const float4*)b1)[pass * 4 + ch * 2 + 1];
        float o[8];
        o[0] = fmaxf(bb0.x + di * acc[0], 0.f); o[1] = fmaxf(bb0.y + di * acc[1], 0.f);
        o[2] = fmaxf(bb0.z + di * acc[2], 0.f); o[3] = fmaxf(bb0.w + di * acc[3], 0.f);
        o[4] = fmaxf(bb1.x + di * acc[4], 0.f); o[5] = fmaxf(bb1.y + di * acc[5], 0.f);
        o[6] = fmaxf(bb1.z + di * acc[6], 0.f); o[7] = fmaxf(bb1.w + di * acc[7], 0.f);
        __half2 p0 = __float22half2_rn(make_float2(o[0], o[1]));
        __half2 p1 = __float22half2_rn(make_float2(o[2], o[3]));
        __half2 p2 = __float22half2_rn(make_float2(o[4], o[5]));
        __half2 p3 = __float22half2_rn(make_float2(o[6], o[7]));
        uint4 packed;
        packed.x = *(unsigned*)&p0; packed.y = *(unsigned*)&p1;
        packed.z = *(unsigned*)&p2; packed.w = *(unsigned*)&p3;
        // layout: agg1h[node*32 + pass*16 + ch*8 .. +8)  ->  uint4 index node*4 + pass*2 + ch
        ((uint4*)agg1h)[(size_t)node * 4 + pass * 2 + ch] = packed;
    }
}

// ---------------- layer 2 GEMM: reads fp16 relu'd h (half the bytes, no fmax) ----------------
__global__ __launch_bounds__(256) void gemm2_kernel(
        const __half* __restrict__ agg1h, const float* __restrict__ W2,
        const float* __restrict__ dinv, __half* __restrict__ g2h, int n) {
    __shared__ float sW[32 * 16];     // sW[k*16+c] = W2[c*32+k]
    __shared__ float sH[64 * 33];     // padded (32 cols + 1)
    int tid = threadIdx.x;
    for (int idx = tid; idx < 512; idx += 256) {
        int k = idx >> 4, c = idx & 15;
        sW[idx] = W2[c * 32 + k];
    }
    int row0 = blockIdx.x * 64;
    {   // 256 threads = 64 rows x 4 quads; each loads 8 halves (uint4)
        int r = tid >> 2, q = tid & 3;
        int grow = row0 + r;
        uint4 v = make_uint4(0, 0, 0, 0);
        if (grow < n) v = ((const uint4*)agg1h)[(size_t)grow * 4 + q];
        float* dp = &sH[r * 33 + q * 8];
        float2 f;
        f = u2f2(v.x); dp[0] = f.x; dp[1] = f.y;
        f = u2f2(v.y); dp[2] = f.x; dp[3] = f.y;
        f = u2f2(v.z); dp[4] = f.x; dp[5] = f.y;
        f = u2f2(v.w); dp[6] = f.x; dp[7] = f.y;
    }
    __syncthreads();
    int r = tid >> 2, cg = tid & 3;
    const float4* sW4 = (const float4*)sW;
    float4 acc = make_float4(0.f, 0.f, 0.f, 0.f);
#pragma unroll
    for (int k = 0; k < 32; ++k) {
        float hk = sH[r * 33 + k];
        float4 w = sW4[k * 4 + cg];
        acc.x += hk * w.x; acc.y += hk * w.y; acc.z += hk * w.z; acc.w += hk * w.w;
    }
    int grow = row0 + r;
    if (grow < n) {
        float di = dinv[grow];
        __half2 h0 = __float22half2_rn(make_float2(acc.x * di, acc.y * di));
        __half2 h1 = __float22half2_rn(make_float2(acc.z * di, acc.w * di));
        uint2 packed;
        packed.x = *(unsigned*)&h0;
        packed.y = *(unsigned*)&h1;
        ((uint2*)g2h)[(size_t)grow * 4 + cg] = packed;
    }
}

// ---------------- layer 2 aggregation: 4 threads/node, uint4 gathers ----------------
__global__ __launch_bounds__(256) void agg2_kernel(
        const int* __restrict__ rowptr, const int* __restrict__ adj2,
        const float* __restrict__ dinv, const __half* __restrict__ g2h,
        const float* __restrict__ b2, __half* __restrict__ zh, int n) {
    int t = blockIdx.x * blockDim.x + threadIdx.x;
    int node = t >> 2;
    if (node >= n) return;
    int sub = t & 3;
    int slice = sub >> 1, ch = sub & 1;
    const uint4* G = (const uint4*)g2h;        // row i = G[i*2 + ch]
    float acc[8] = {0.f, 0.f, 0.f, 0.f, 0.f, 0.f, 0.f, 0.f};
    if (slice == 0)
        acc8(acc, G[(size_t)node * 2 + ch]);
    int beg = rowptr[node], end = rowptr[node + 1];
    int deg = end - beg;
    int half0 = (deg + 1) >> 1;
    int j    = beg + slice * half0;
    int jend = slice ? end : beg + half0;
    for (; j + 7 < jend; j += 8) {
        int s0 = adj2[j],     s1 = adj2[j + 1], s2 = adj2[j + 2], s3 = adj2[j + 3];
        int s4 = adj2[j + 4], s5 = adj2[j + 5], s6 = adj2[j + 6], s7 = adj2[j + 7];
        uint4 v0 = G[(size_t)s0 * 2 + ch];
        uint4 v1 = G[(size_t)s1 * 2 + ch];
        uint4 v2 = G[(size_t)s2 * 2 + ch];
        uint4 v3 = G[(size_t)s3 * 2 + ch];
        uint4 v4 = G[(size_t)s4 * 2 + ch];
        uint4 v5 = G[(size_t)s5 * 2 + ch];
        uint4 v6 = G[(size_t)s6 * 2 + ch];
        uint4 v7 = G[(size_t)s7 * 2 + ch];
        acc8(acc, v0); acc8(acc, v1); acc8(acc, v2); acc8(acc, v3);
        acc8(acc, v4); acc8(acc, v5); acc8(acc, v6); acc8(acc, v7);
    }
    for (; j + 3 < jend; j += 4) {
        int s0 = adj2[j], s1 = adj2[j + 1], s2 = adj2[j + 2], s3 = adj2[j + 3];
        uint4 v0 = G[(size_t)s0 * 2 + ch];
        uint4 v1 = G[(size_t)s1 * 2 + ch];
        uint4 v2 = G[(size_t)s2 * 2 + ch];
        uint4 v3 = G[(size_t)s3 * 2 + ch];
        acc8(acc, v0); acc8(acc, v1); acc8(acc, v2); acc8(acc, v3);
    }
    for (; j < jend; ++j)
        acc8(acc, G[(size_t)adj2[j] * 2 + ch]);
#pragma unroll
    for (int k = 0; k < 8; ++k)
        acc[k] += __shfl_xor(acc[k], 2, 64);
    if (slice == 0) {
        float di = dinv[node];
        float4 bb0 = ((const float4*)b2)[ch * 2];
        float4 bb1 = ((const float4*)b2)[ch * 2 + 1];
        __half2 p0 = __float22half2_rn(make_float2(bb0.x + di * acc[0], bb0.y + di * acc[1]));
        __half2 p1 = __float22half2_rn(make_float2(bb0.z + di * acc[2], bb0.w + di * acc[3]));
        __half2 p2 = __float22half2_rn(make_float2(bb1.x + di * acc[4], bb1.y + di * acc[5]));
        __half2 p3 = __float22half2_rn(make_float2(bb1.z + di * acc[6], bb1.w + di * acc[7]));
        uint4 packed;
        packed.x = *(unsigned*)&p0; packed.y = *(unsigned*)&p1;
        packed.z = *(unsigned*)&p2; packed.w = *(unsigned*)&p3;
        ((uint4*)zh)[(size_t)node * 2 + ch] = packed;
    }
}

// ---------------- decode: pair-lane, 2 edges per lane-pair ----------------
__global__ __launch_bounds__(256) void decode_kernel(
        const int* __restrict__ src, const int* __restrict__ dst,
        const __half* __restrict__ zh, float* __restrict__ out, int e) {
    int t = blockIdx.x * blockDim.x + threadIdx.x;
    int pair = t >> 1;                 // pair of consecutive edges
    int e0 = pair * 2;
    if (e0 >= e) return;
    int half = t & 1;
    u64 sv = *(const u64*)(src + e0);
    u64 dv = *(const u64*)(dst + e0);
    int s0 = (int)(unsigned)sv, s1 = (int)(sv >> 32);
    int d0 = (int)(unsigned)dv, d1 = (int)(dv >> 32);
    uint4 a0 = *((const uint4*)(zh + (size_t)s0 * 16) + half);
    uint4 b0 = *((const uint4*)(zh + (size_t)d0 * 16) + half);
    uint4 a1 = *((const uint4*)(zh + (size_t)s1 * 16) + half);
    uint4 b1 = *((const uint4*)(zh + (size_t)d1 * 16) + half);
    float p0 = 0.f, p1 = 0.f;
    p0 = dot2acc(a0.x, b0.x, p0); p0 = dot2acc(a0.y, b0.y, p0);
    p0 = dot2acc(a0.z, b0.z, p0); p0 = dot2acc(a0.w, b0.w, p0);
    p1 = dot2acc(a1.x, b1.x, p1); p1 = dot2acc(a1.y, b1.y, p1);
    p1 = dot2acc(a1.z, b1.z, p1); p1 = dot2acc(a1.w, b1.w, p1);
    float t0 = p0 + __shfl_xor(p0, 1, 64);
    float t1 = p1 + __shfl_xor(p1, 1, 64);
    if (half == 0) {
        float2 o;
        o.x = 1.0f / (1.0f + expf(-t0));
        o.y = 1.0f / (1.0f + expf(-t1));
        ((float2*)out)[pair] = o;
    }
}

extern "C" void kernel_launch(void* const* d_in, const int* in_sizes, int n_in,
                              void* d_out, int out_size, void* d_ws, size_t ws_size,
                              hipStream_t stream) {
    const float* x   = (const float*)d_in[0];
    const int* eidx  = (const int*)d_in[1];
    const float* W1  = (const float*)d_in[2];
    const float* b1  = (const float*)d_in[3];
    const float* W2  = (const float*)d_in[4];
    const float* b2  = (const float*)d_in[5];
    float* out = (float*)d_out;

    const int n = NN;
    const int e = NE;
    const int* src = eidx;
    const int* dst = eidx + e;

    // workspace layout (all segments 16B-aligned)
    int* bhist   = (int*)d_ws;                 // 512
    int* boffs   = bhist + 512;                // 512
    int* cursor  = boffs + 512;                // 512
    int* rowptr  = cursor + 512;               // NN+1 (pad 100004)
    int* adj     = rowptr + 100004;            // NE packed (dead after csr)
    int* adj2    = adj + e;                    // NE node-sorted srcs
    float* dinv  = (float*)(adj2 + e);         // NN
    __half* g1a  = (__half*)adj;               // alias: NN*16 halves (3.2MB) - cols 0..15
    __half* g1b  = g1a + (size_t)n * 16;       // NN*16 halves (3.2MB) - cols 16..31
    __half* agg1h = (__half*)(dinv + n);       // NN*32 halves (relu'd h, 6.4MB)
    __half* g2h  = agg1h + (size_t)n * 32;     // NN*16 halves
    __half* zh   = g2h + (size_t)n * 16;       // NN*16 halves
    int* part    = (int*)(zh + (size_t)n * 16);// NBH*NB partial histograms

    dim3 blk(256);

    // CSR build
    bhist_kernel<<<NBH, blk, 0, stream>>>(dst, part, e);
    bscan_kernel<<<1, 512, 0, stream>>>(part, bhist, boffs, cursor);
    partition_kernel<<<NPART, 512, 0, stream>>>(src, dst, cursor, adj, e);
    csr_kernel<<<NB, 512, 0, stream>>>(bhist, boffs, adj, adj2, rowptr, dinv, n);

    // layer 1
    gemm1_kernel<<<(n + 31) / 32, blk, 0, stream>>>(x, W1, dinv, g1a, g1b, n);
    agg1_kernel<<<(n * 4 + 255) / 256, blk, 0, stream>>>(rowptr, adj2, dinv, g1a, b1, agg1h, n, 0);
    agg1_kernel<<<(n * 4 + 255) / 256, blk, 0, stream>>>(rowptr, adj2, dinv, g1b, b1, agg1h, n, 1);

    // layer 2
    gemm2_kernel<<<(n + 63) / 64, blk, 0, stream>>>(agg1h, W2, dinv, g2h, n);
    agg2_kernel<<<(n * 4 + 255) / 256, blk, 0, stream>>>(rowptr, adj2, dinv, g2h, b2, zh, n);

    // decode: lane-pair handles 2 edges -> e threads total
    decode_kernel<<<(e + 255) / 256, blk, 0, stream>>>(src, dst, zh, out, e);
}